// Round 2
// baseline (191.754 us; speedup 1.0000x reference)
//
#include <hip/hip_runtime.h>

// Problem constants
#define H_ROWS 4096
#define IN_F   4096
#define OUT_F  4096

typedef __bf16 bf16;
typedef __bf16 bf16x4 __attribute__((ext_vector_type(4)));
typedef __bf16 bf16x8 __attribute__((ext_vector_type(8)));
typedef float  f32x4  __attribute__((ext_vector_type(4)));

// ---------------------------------------------------------------------------
// Kernel 1 (R4 rewrite, resubmitted R5 after container failure): one WAVE per
// matrix row, zero synchronization.
//   Key identity: 64 lanes x float4 = 256 floats = TILE_H, so the fold
//   xs[r][t] = sum_v x[r][v*256+t] is lane-local: lane l accumulating
//   float4 indices i*64+l (i=0..15) holds exactly t = 4l..4l+3, because
//   (f*4+c) & 255 = (f&63)*4 + c and f&63 = l.
//   -> each wave: 16 contiguous 1KB load transactions + one 512B bf16x4
//      store. No LDS, no __syncthreads, no serial tail, no block-retire
//      convoy (R3's limiter: barrier+tail drained the load pipe every
//      16KB -> 2.7 TB/s; this shape is pure streaming).
//   Two halves of 8 loads keep live VGPRs ~48 -> full 32 waves/CU.
//   gw < 4096 -> x row gw; gw >= 4096 -> weight row gw-4096 (uniform
//   per-wave branch, contiguous streams per block: 4 rows = 64KB).
// ---------------------------------------------------------------------------
__global__ __launch_bounds__(256) void reduce_kernel(
    const float* __restrict__ x, const float* __restrict__ w,
    bf16* __restrict__ xs, bf16* __restrict__ wsT)
{
    const int tid  = threadIdx.x;
    const int lane = tid & 63;
    const int gw   = blockIdx.x * 4 + (tid >> 6);   // global wave id 0..8191
    const int isW  = gw >> 12;                      // 0: x-row, 1: w-row
    const int r    = gw & 4095;

    const float4* __restrict__ s =
        (const float4*)(isW ? w : x) + r * (IN_F / 4) + lane;
    bf16* __restrict__ dst = (isW ? wsT : xs) + r * 256 + lane * 4;

    float4 acc;
    acc.x = 0.f; acc.y = 0.f; acc.z = 0.f; acc.w = 0.f;

    #pragma unroll
    for (int h = 0; h < 2; ++h) {
        float4 v[8];
        #pragma unroll
        for (int i = 0; i < 8; ++i)
            v[i] = s[(h * 8 + i) * 64];
        #pragma unroll
        for (int i = 0; i < 8; ++i) {
            acc.x += v[i].x;
            acc.y += v[i].y;
            acc.z += v[i].z;
            acc.w += v[i].w;
        }
    }

    bf16x4 o;
    o[0] = (bf16)acc.x; o[1] = (bf16)acc.y;
    o[2] = (bf16)acc.z; o[3] = (bf16)acc.w;
    *(bf16x4*)dst = o;
}

// ---------------------------------------------------------------------------
// Kernel 2: NT GEMM  out[m][n] = sum_k A[m][k]*B[n][k] + bias[n]
//   A = xs  (M=4096, K=256) bf16 row-major
//   B = wsT (N=4096, K=256) bf16 row-major
// m97 structure: 128x128 block tile, BK=32, global_load_lds width=16,
// 4 waves in 2x2, each wave 64x64 = 4x4 tiles of 16x16x32 MFMA.
// (unchanged this round — isolating the reduce fix)
// ---------------------------------------------------------------------------
__global__ __launch_bounds__(256) void gemm_bt_kernel(
    const bf16* __restrict__ A, const bf16* __restrict__ B,
    const float* __restrict__ bias, float* __restrict__ out)
{
    __shared__ bf16 As[128 * 32];   // 8 KB
    __shared__ bf16 Bs[128 * 32];   // 8 KB

    const int m0   = blockIdx.y * 128;
    const int n0   = blockIdx.x * 128;
    const int tid  = threadIdx.x;
    const int lane = tid & 63;
    const int w    = tid >> 6;
    const int wm   = (w & 1) * 64;
    const int wn   = (w >> 1) * 64;
    const int l15  = lane & 15;
    const int quad = lane >> 4;

    f32x4 acc[4][4] = {};

    for (int kk = 0; kk < 8; ++kk) {
        const int k0 = kk * 32;
        #pragma unroll
        for (int c = 0; c < 2; ++c) {
            const int chunk = c * 256 + tid;
            const int row   = chunk >> 2;      // 0..127
            const int kc    = chunk & 3;       // 16B chunk within 64B row
            const bf16* ga = A + (m0 + row) * 256 + k0 + kc * 8;
            const bf16* gb = B + (n0 + row) * 256 + k0 + kc * 8;
            __builtin_amdgcn_global_load_lds(
                (const __attribute__((address_space(1))) void*)ga,
                (__attribute__((address_space(3))) void*)(As + chunk * 8), 16, 0, 0);
            __builtin_amdgcn_global_load_lds(
                (const __attribute__((address_space(1))) void*)gb,
                (__attribute__((address_space(3))) void*)(Bs + chunk * 8), 16, 0, 0);
        }
        __syncthreads();

        bf16x8 af[4], bfr[4];
        #pragma unroll
        for (int t = 0; t < 4; ++t) {
            af[t]  = *(const bf16x8*)(As + (wm + t * 16 + l15) * 32 + quad * 8);
            bfr[t] = *(const bf16x8*)(Bs + (wn + t * 16 + l15) * 32 + quad * 8);
        }
        #pragma unroll
        for (int mt = 0; mt < 4; ++mt)
            #pragma unroll
            for (int nt = 0; nt < 4; ++nt)
                acc[mt][nt] = __builtin_amdgcn_mfma_f32_16x16x32_bf16(
                    af[mt], bfr[nt], acc[mt][nt], 0, 0, 0);
        __syncthreads();
    }

    #pragma unroll
    for (int nt = 0; nt < 4; ++nt) {
        const int col = n0 + wn + nt * 16 + l15;
        const float bv = bias[col];
        #pragma unroll
        for (int mt = 0; mt < 4; ++mt) {
            const int rbase = m0 + wm + mt * 16 + quad * 4;
            #pragma unroll
            for (int r = 0; r < 4; ++r)
                out[(rbase + r) * OUT_F + col] = acc[mt][nt][r] + bv;
        }
    }
}

extern "C" void kernel_launch(void* const* d_in, const int* in_sizes, int n_in,
                              void* d_out, int out_size, void* d_ws, size_t ws_size,
                              hipStream_t stream)
{
    const float* x      = (const float*)d_in[0];  // (4096, 4096)
    const float* weight = (const float*)d_in[1];  // (4096, 4096)
    const float* bias   = (const float*)d_in[2];  // (4096,)
    float* out = (float*)d_out;                   // (4096, 4096) f32

    bf16* xs  = (bf16*)d_ws;                      // 4096*256 bf16 = 2 MB
    bf16* wsT = xs + 4096 * 256;                  // 4096*256 bf16 = 2 MB

    reduce_kernel<<<2048, 256, 0, stream>>>(x, weight, xs, wsT);
    gemm_bt_kernel<<<dim3(32, 32), 256, 0, stream>>>(xs, wsT, bias, out);
}